// Round 9
// baseline (4293.381 us; speedup 1.0000x reference)
//
#include <hip/hip_runtime.h>
#include <cstdint>
#include <cstddef>

#define IN_DIM 256
#define HID    512
#define TSTEPS 8
#define ROWS   16
#define NTHR   512     // 128 col-slots x 4 row-groups
#define RPT    4       // rows per thread
#define KC8    48      // OpenBLAS kc=384 boundary in 8-k units
#define KC4    96      // kc=384 boundary in floats/4 (head loops)

// ---- pack: Pf[(k*128+jj)*4 + c] = W[jj+128c][k]  (LDS-tiled, coalesced)
__global__ void wpack4(const float* __restrict__ W, float* __restrict__ Pf, int K) {
  __shared__ float tl[32][33];
  const int k0 = blockIdx.x * 32;
  const int j0 = blockIdx.y * 32;            // j in [0,512)
  const int tx = threadIdx.x & 31, ty = threadIdx.x >> 5;   // 32x8
#pragma unroll
  for (int i = 0; i < 32; i += 8)
    tl[ty + i][tx] = W[(size_t)(j0 + ty + i) * K + (k0 + tx)];
  __syncthreads();
  const int c = j0 >> 7;
  const int jjb = j0 & 127;
#pragma unroll
  for (int i = 0; i < 32; i += 8) {
    int k = k0 + ty + i;
    Pf[((size_t)k * 128 + (jjb + tx)) * 4 + c] = tl[tx][ty + i];
  }
}

// ---- u8-spike GEMM core (layers 2/3): ascending-k fp32 fma chain, BLAS GEBP
// order, bit-identical (spike {0,1} -> cvt_f32_ubyte exact). Per i8 per thread:
// 4 broadcast ds_read_b64 + 8 coalesced dwordx4 + 128 fma + 32 cvt.
__device__ __forceinline__ void gemm_u8(const unsigned char* __restrict__ spk,
                                        int rbase, const float4* __restrict__ P,
                                        int j1, int i8b, int i8e,
                                        float (&A)[RPT][4]) {
#pragma unroll 1
  for (int i8 = i8b; i8 < i8e; ++i8) {
    const float4* wp = P + ((size_t)i8 << 10) + j1;
    float4 w0 = wp[0],   w1 = wp[128], w2 = wp[256], w3 = wp[384];
    float4 w4 = wp[512], w5 = wp[640], w6 = wp[768], w7 = wp[896];
    uint2 sv[RPT];
#pragma unroll
    for (int r = 0; r < RPT; ++r)
      sv[r] = *reinterpret_cast<const uint2*>(spk + ((rbase + r) << 9) + (i8 << 3));
#pragma unroll
    for (int r = 0; r < RPT; ++r) {
      float f0 = (float)(sv[r].x & 0xffu);
      float f1 = (float)((sv[r].x >> 8) & 0xffu);
      float f2 = (float)((sv[r].x >> 16) & 0xffu);
      float f3 = (float)(sv[r].x >> 24);
      float f4 = (float)(sv[r].y & 0xffu);
      float f5 = (float)((sv[r].y >> 8) & 0xffu);
      float f6 = (float)((sv[r].y >> 16) & 0xffu);
      float f7 = (float)(sv[r].y >> 24);
      float a0 = A[r][0], a1 = A[r][1], a2 = A[r][2], a3 = A[r][3];
      a0 = fmaf(f0, w0.x, a0); a1 = fmaf(f0, w0.y, a1); a2 = fmaf(f0, w0.z, a2); a3 = fmaf(f0, w0.w, a3);
      a0 = fmaf(f1, w1.x, a0); a1 = fmaf(f1, w1.y, a1); a2 = fmaf(f1, w1.z, a2); a3 = fmaf(f1, w1.w, a3);
      a0 = fmaf(f2, w2.x, a0); a1 = fmaf(f2, w2.y, a1); a2 = fmaf(f2, w2.z, a2); a3 = fmaf(f2, w2.w, a3);
      a0 = fmaf(f3, w3.x, a0); a1 = fmaf(f3, w3.y, a1); a2 = fmaf(f3, w3.z, a2); a3 = fmaf(f3, w3.w, a3);
      a0 = fmaf(f4, w4.x, a0); a1 = fmaf(f4, w4.y, a1); a2 = fmaf(f4, w4.z, a2); a3 = fmaf(f4, w4.w, a3);
      a0 = fmaf(f5, w5.x, a0); a1 = fmaf(f5, w5.y, a1); a2 = fmaf(f5, w5.z, a2); a3 = fmaf(f5, w5.w, a3);
      a0 = fmaf(f6, w6.x, a0); a1 = fmaf(f6, w6.y, a1); a2 = fmaf(f6, w6.z, a2); a3 = fmaf(f6, w6.w, a3);
      a0 = fmaf(f7, w7.x, a0); a1 = fmaf(f7, w7.y, a1); a2 = fmaf(f7, w7.z, a2); a3 = fmaf(f7, w7.w, a3);
      A[r][0] = a0; A[r][1] = a1; A[r][2] = a2; A[r][3] = a3;
    }
  }
}

// ---- f32-obs GEMM core (layer 1, K=256 single panel)
__device__ __forceinline__ void gemm_obs(const float* __restrict__ obsT,
                                         int rbase, const float4* __restrict__ P,
                                         int j1, float (&A)[RPT][4]) {
#pragma unroll 1
  for (int i4 = 0; i4 < IN_DIM / 4; ++i4) {
    const float4* wp = P + ((size_t)i4 << 9) + j1;
    float4 w0 = wp[0], w1 = wp[128], w2 = wp[256], w3 = wp[384];
#pragma unroll
    for (int r = 0; r < RPT; ++r) {
      float4 o = *reinterpret_cast<const float4*>(obsT + ((rbase + r) << 8) + (i4 << 2));
      float a0 = A[r][0], a1 = A[r][1], a2 = A[r][2], a3 = A[r][3];
      a0 = fmaf(o.x, w0.x, a0); a1 = fmaf(o.x, w0.y, a1); a2 = fmaf(o.x, w0.z, a2); a3 = fmaf(o.x, w0.w, a3);
      a0 = fmaf(o.y, w1.x, a0); a1 = fmaf(o.y, w1.y, a1); a2 = fmaf(o.y, w1.z, a2); a3 = fmaf(o.y, w1.w, a3);
      a0 = fmaf(o.z, w2.x, a0); a1 = fmaf(o.z, w2.y, a1); a2 = fmaf(o.z, w2.z, a2); a3 = fmaf(o.z, w2.w, a3);
      a0 = fmaf(o.w, w3.x, a0); a1 = fmaf(o.w, w3.y, a1); a2 = fmaf(o.w, w3.z, a2); a3 = fmaf(o.w, w3.w, a3);
      A[r][0] = a0; A[r][1] = a1; A[r][2] = a2; A[r][3] = a3;
    }
  }
}

// (512,1): cap 512 VGPR; live set ~170 -> expect 2 waves/SIMD, NO spills.
__launch_bounds__(NTHR, 1)
__global__ void snn_net(const float* __restrict__ obs,
                        const float4* __restrict__ pP1, const float* __restrict__ pb1_,
                        const float4* __restrict__ pP2, const float* __restrict__ pb2_,
                        const float4* __restrict__ pP3, const float* __restrict__ pb3_,
                        const float* __restrict__ paw, const float* __restrict__ pab,
                        const float4* __restrict__ vP1, const float* __restrict__ vb1_,
                        const float4* __restrict__ vP2, const float* __restrict__ vb2_,
                        const float4* __restrict__ vP3, const float* __restrict__ vb3_,
                        const float* __restrict__ vhw, const float* __restrict__ vhb,
                        const float* __restrict__ log_std,
                        float* __restrict__ out, int B) {
  // XCD split: policy on XCD 0-3, value on 4-7 (each XCD L2 holds one net).
  const int bid = blockIdx.x;
  const int xcd = bid & 7;
  const int is_value = xcd >> 2;
  const int tile = (bid >> 3) * 4 + (xcd & 3);
  const float4* P1 = is_value ? vP1 : pP1;  const float* b1 = is_value ? vb1_ : pb1_;
  const float4* P2 = is_value ? vP2 : pP2;  const float* b2 = is_value ? vb2_ : pb2_;
  const float4* P3 = is_value ? vP3 : pP3;  const float* b3 = is_value ? vb3_ : pb3_;
  const float* Wh  = is_value ? vhw : paw;  const float* bh = is_value ? vhb : pab;

  // LDS 64KB: obsT f32 [0,16K); c1 packed f32 [16K,48K); spkA u8 [48K,56K);
  // spkB u8 [56K,64K). meanT f32 [0,32K) reuses obsT+c1-low after the t-loop.
  __shared__ __align__(16) unsigned char lraw[65536];
  float* obsT = (float*)lraw;
  float4* c1p = (float4*)(lraw + 16384);          // [(row*128+j1)] float4 (4 cols)
  unsigned char* spkA = lraw + 49152;
  unsigned char* spkB = lraw + 57344;
  float* meanT = (float*)lraw;

  const int tid = threadIdx.x;
  const int j1 = tid & 127;
  const int rbase = (tid >> 7) * RPT;   // 0,4,8,12
  const int r0 = tile * ROWS;

  // ---- stage obs tile (coalesced float4)
  {
    const float4* src = reinterpret_cast<const float4*>(obs + (size_t)r0 * IN_DIM);
    float4* dst = reinterpret_cast<float4*>(obsT);
    for (int e = tid; e < ROWS * IN_DIM / 4; e += NTHR) dst[e] = src[e];
  }
  __syncthreads();

  // ---- layer-1 currents (K=256 single BLAS panel; bias AFTER sum) -> LDS
  {
    float Sa[RPT][4];
#pragma unroll
    for (int r = 0; r < RPT; ++r)
#pragma unroll
      for (int c = 0; c < 4; ++c) Sa[r][c] = 0.f;
    gemm_obs(obsT, rbase, P1, j1, Sa);
    const float bb0 = b1[j1], bb1 = b1[j1 + 128], bb2 = b1[j1 + 256], bb3 = b1[j1 + 384];
#pragma unroll
    for (int r = 0; r < RPT; ++r) {
      float4 v;
      v.x = __fadd_rn(Sa[r][0], bb0);
      v.y = __fadd_rn(Sa[r][1], bb1);
      v.z = __fadd_rn(Sa[r][2], bb2);
      v.w = __fadd_rn(Sa[r][3], bb3);
      c1p[(rbase + r) * 128 + j1] = v;
    }
  }
  __syncthreads();

  // ---- fp32 membranes (registers); layer-3 spike counts packed 4b fields
  float m1[RPT][4], m2[RPT][4], m3[RPT][4];
  unsigned cnt32[2] = {0u, 0u};   // field (r,c): word r>>1, nibble (r&1)*4+c
#pragma unroll
  for (int r = 0; r < RPT; ++r)
#pragma unroll
    for (int c = 0; c < 4; ++c) { m1[r][c] = 0.f; m2[r][c] = 0.f; m3[r][c] = 0.f; }

  const float bias2[4] = { b2[j1], b2[j1 + 128], b2[j1 + 256], b2[j1 + 384] };
  const float bias3[4] = { b3[j1], b3[j1 + 128], b3[j1 + 256], b3[j1 + 384] };

#pragma unroll 1
  for (int t = 0; t < TSTEPS; ++t) {
    // ---- LIF layer 1: m = RN(RN(0.95*m)+cur); spike u8 {0,1} -> spkA
#pragma unroll
    for (int r = 0; r < RPT; ++r) {
      float4 cur = c1p[(rbase + r) * 128 + j1];
      float cc[4] = { cur.x, cur.y, cur.z, cur.w };
#pragma unroll
      for (int c = 0; c < 4; ++c) {
        m1[r][c] = __fadd_rn(__fmul_rn(0.95f, m1[r][c]), cc[c]);
        bool f = m1[r][c] > 1.0f;
        m1[r][c] = __fsub_rn(m1[r][c], f ? 1.0f : 0.0f);
        spkA[((rbase + r) << 9) + j1 + (c << 7)] = f ? 1 : 0;
      }
    }
    __syncthreads();   // A ready; also fences gemm3(t-1) B-reads before LIF2 B-writes

    // ---- layer 2: two BLAS panels (kc=384), RN(S0+S1), then +bias
    {
      float S0[RPT][4], S1[RPT][4];
#pragma unroll
      for (int r = 0; r < RPT; ++r)
#pragma unroll
        for (int c = 0; c < 4; ++c) { S0[r][c] = 0.f; S1[r][c] = 0.f; }
      gemm_u8(spkA, rbase, P2, j1, 0, KC8, S0);
      gemm_u8(spkA, rbase, P2, j1, KC8, HID >> 3, S1);
#pragma unroll
      for (int r = 0; r < RPT; ++r) {
#pragma unroll
        for (int c = 0; c < 4; ++c) {
          float cur = __fadd_rn(__fadd_rn(S0[r][c], S1[r][c]), bias2[c]);
          m2[r][c] = __fadd_rn(__fmul_rn(0.95f, m2[r][c]), cur);
          bool f = m2[r][c] > 1.0f;
          m2[r][c] = __fsub_rn(m2[r][c], f ? 1.0f : 0.0f);
          spkB[((rbase + r) << 9) + j1 + (c << 7)] = f ? 1 : 0;
        }
      }
    }
    __syncthreads();   // B ready; gemm2 A-reads done before next LIF1 A-writes

    // ---- layer 3: same structure; packed spike counts
    {
      float S0[RPT][4], S1[RPT][4];
#pragma unroll
      for (int r = 0; r < RPT; ++r)
#pragma unroll
        for (int c = 0; c < 4; ++c) { S0[r][c] = 0.f; S1[r][c] = 0.f; }
      gemm_u8(spkB, rbase, P3, j1, 0, KC8, S0);
      gemm_u8(spkB, rbase, P3, j1, KC8, HID >> 3, S1);
#pragma unroll
      for (int r = 0; r < RPT; ++r) {
#pragma unroll
        for (int c = 0; c < 4; ++c) {
          float cur = __fadd_rn(__fadd_rn(S0[r][c], S1[r][c]), bias3[c]);
          m3[r][c] = __fadd_rn(__fmul_rn(0.95f, m3[r][c]), cur);
          bool f = m3[r][c] > 1.0f;
          m3[r][c] = __fsub_rn(m3[r][c], f ? 1.0f : 0.0f);
          cnt32[r >> 1] += f ? (1u << (((r & 1) * 4 + c) * 4)) : 0u;
        }
      }
    }
    // no barrier: next LIF1 writes spkA only; fenced by the barrier after it.
  }
  __syncthreads();   // all t-loop LDS traffic done before meanT overwrites

  // ---- mean spikes (count/8 exact) into f32 tile [row][col]
#pragma unroll
  for (int r = 0; r < RPT; ++r)
#pragma unroll
    for (int c = 0; c < 4; ++c)
      meanT[(rbase + r) * HID + j1 + (c << 7)] =
          (float)((cnt32[r >> 1] >> (((r & 1) * 4 + c) * 4)) & 15u) * 0.125f;
  __syncthreads();

  // ---- heads (BLAS two-panel structure, kc=384)
  if (is_value == 0) {
    if (tid < ROWS * 6) {
      int r = tid / 6, k = tid % 6;
      const float* wr = Wh + (size_t)k * HID;
      float S0h = 0.f, S1h = 0.f;
      for (int i = 0; i < 4 * KC4; ++i)   S0h = fmaf(meanT[r * HID + i], wr[i], S0h);
      for (int i = 4 * KC4; i < HID; ++i) S1h = fmaf(meanT[r * HID + i], wr[i], S1h);
      out[(size_t)(r0 + r) * 6 + k] = __fadd_rn(__fadd_rn(S0h, S1h), bh[k]);
      out[(size_t)B * 6 + (size_t)(r0 + r) * 6 + k] = log_std[k];
    }
  } else {
    if (tid < ROWS) {
      int r = tid;
      float S0h = 0.f, S1h = 0.f;
      for (int i = 0; i < 4 * KC4; ++i)   S0h = fmaf(meanT[r * HID + i], Wh[i], S0h);
      for (int i = 4 * KC4; i < HID; ++i) S1h = fmaf(meanT[r * HID + i], Wh[i], S1h);
      out[(size_t)B * 12 + (size_t)(r0 + r)] = __fadd_rn(__fadd_rn(S0h, S1h), bh[0]);
    }
  }
}

// ---------------- fallback (round-3 kernel, proven; used if ws too small) --------
#define NTHRB 512
#define RPTB  8
template<int PITCH4>
__device__ __forceinline__ void gemm_f32(const float* __restrict__ sl, int rbase,
                                         const float4* __restrict__ wra,
                                         const float4* __restrict__ wrb,
                                         int i4begin, int i4end,
                                         float a0[RPTB], float a1[RPTB]) {
  const float4* slv = reinterpret_cast<const float4*>(sl);
  for (int i4 = i4begin; i4 < i4end; ++i4) {
    float4 wa = wra[i4];
    float4 wb = wrb[i4];
#pragma unroll
    for (int r = 0; r < RPTB; ++r) {
      float4 s = slv[(rbase + r) * PITCH4 + i4];
      a0[r] = fmaf(s.w, wa.w, fmaf(s.z, wa.z, fmaf(s.y, wa.y, fmaf(s.x, wa.x, a0[r]))));
      a1[r] = fmaf(s.w, wb.w, fmaf(s.z, wb.z, fmaf(s.y, wb.y, fmaf(s.x, wb.x, a1[r]))));
    }
  }
}

__launch_bounds__(NTHRB, 2)
__global__ void snn_net_base(const float* __restrict__ obs,
                             const float* __restrict__ pW1, const float* __restrict__ pb1_,
                             const float* __restrict__ pW2, const float* __restrict__ pb2_,
                             const float* __restrict__ pW3, const float* __restrict__ pb3_,
                             const float* __restrict__ paw, const float* __restrict__ pab,
                             const float* __restrict__ vW1, const float* __restrict__ vb1_,
                             const float* __restrict__ vW2, const float* __restrict__ vb2_,
                             const float* __restrict__ vW3, const float* __restrict__ vb3_,
                             const float* __restrict__ vhw, const float* __restrict__ vhb,
                             const float* __restrict__ log_std,
                             float* __restrict__ out, int B) {
  const int is_value = blockIdx.y;
  const float* W1 = is_value ? vW1 : pW1;  const float* b1 = is_value ? vb1_ : pb1_;
  const float* W2 = is_value ? vW2 : pW2;  const float* b2 = is_value ? vb2_ : pb2_;
  const float* W3 = is_value ? vW3 : pW3;  const float* b3 = is_value ? vb3_ : pb3_;
  const float* Wh = is_value ? vhw : paw;  const float* bh = is_value ? vhb : pab;

  __shared__ float sl[ROWS * HID];
  const int tid = threadIdx.x;
  const int r0 = blockIdx.x * ROWS;
  const int j1 = tid & 255, j2 = j1 + 256;
  const int rbase = (tid >> 8) * RPTB;

  for (int e = tid; e < ROWS * IN_DIM; e += NTHRB)
    sl[e] = obs[(size_t)r0 * IN_DIM + e];
  __syncthreads();

  float c1a[RPTB], c1b[RPTB];
  {
    float Sa[RPTB], Sb[RPTB];
#pragma unroll
    for (int r = 0; r < RPTB; ++r) { Sa[r] = 0.f; Sb[r] = 0.f; }
    gemm_f32<IN_DIM / 4>(sl, rbase,
        reinterpret_cast<const float4*>(W1 + (size_t)j1 * IN_DIM),
        reinterpret_cast<const float4*>(W1 + (size_t)j2 * IN_DIM),
        0, IN_DIM / 4, Sa, Sb);
    const float ba = b1[j1], bb = b1[j2];
#pragma unroll
    for (int r = 0; r < RPTB; ++r) {
      c1a[r] = __fadd_rn(Sa[r], ba);
      c1b[r] = __fadd_rn(Sb[r], bb);
    }
  }
  __syncthreads();

  float m1a[RPTB], m1b[RPTB], m2a[RPTB], m2b[RPTB], m3a[RPTB], m3b[RPTB];
  float sca[RPTB], scb[RPTB];
#pragma unroll
  for (int r = 0; r < RPTB; ++r) {
    m1a[r] = 0.f; m1b[r] = 0.f; m2a[r] = 0.f; m2b[r] = 0.f;
    m3a[r] = 0.f; m3b[r] = 0.f; sca[r] = 0.f; scb[r] = 0.f;
  }

  const float4* w2a = reinterpret_cast<const float4*>(W2 + (size_t)j1 * HID);
  const float4* w2b = reinterpret_cast<const float4*>(W2 + (size_t)j2 * HID);
  const float4* w3a = reinterpret_cast<const float4*>(W3 + (size_t)j1 * HID);
  const float4* w3b = reinterpret_cast<const float4*>(W3 + (size_t)j2 * HID);
  const float bias2a = b2[j1], bias2b = b2[j2];
  const float bias3a = b3[j1], bias3b = b3[j2];

  for (int t = 0; t < TSTEPS; ++t) {
#pragma unroll
    for (int r = 0; r < RPTB; ++r) {
      m1a[r] = __fadd_rn(__fmul_rn(0.95f, m1a[r]), c1a[r]);
      float sa = (m1a[r] > 1.0f) ? 1.0f : 0.0f;
      m1a[r] = __fsub_rn(m1a[r], sa);
      sl[(rbase + r) * HID + j1] = sa;
      m1b[r] = __fadd_rn(__fmul_rn(0.95f, m1b[r]), c1b[r]);
      float sb = (m1b[r] > 1.0f) ? 1.0f : 0.0f;
      m1b[r] = __fsub_rn(m1b[r], sb);
      sl[(rbase + r) * HID + j2] = sb;
    }
    __syncthreads();

    float S0a[RPTB], S0b[RPTB], S1a[RPTB], S1b[RPTB];
#pragma unroll
    for (int r = 0; r < RPTB; ++r) { S0a[r] = 0.f; S0b[r] = 0.f; S1a[r] = 0.f; S1b[r] = 0.f; }
    gemm_f32<HID / 4>(sl, rbase, w2a, w2b, 0, KC4, S0a, S0b);
    gemm_f32<HID / 4>(sl, rbase, w2a, w2b, KC4, HID / 4, S1a, S1b);
    __syncthreads();
#pragma unroll
    for (int r = 0; r < RPTB; ++r) {
      float cura = __fadd_rn(__fadd_rn(S0a[r], S1a[r]), bias2a);
      float curb = __fadd_rn(__fadd_rn(S0b[r], S1b[r]), bias2b);
      m2a[r] = __fadd_rn(__fmul_rn(0.95f, m2a[r]), cura);
      float sa = (m2a[r] > 1.0f) ? 1.0f : 0.0f;
      m2a[r] = __fsub_rn(m2a[r], sa);
      sl[(rbase + r) * HID + j1] = sa;
      m2b[r] = __fadd_rn(__fmul_rn(0.95f, m2b[r]), curb);
      float sb = (m2b[r] > 1.0f) ? 1.0f : 0.0f;
      m2b[r] = __fsub_rn(m2b[r], sb);
      sl[(rbase + r) * HID + j2] = sb;
    }
    __syncthreads();

#pragma unroll
    for (int r = 0; r < RPTB; ++r) { S0a[r] = 0.f; S0b[r] = 0.f; S1a[r] = 0.f; S1b[r] = 0.f; }
    gemm_f32<HID / 4>(sl, rbase, w3a, w3b, 0, KC4, S0a, S0b);
    gemm_f32<HID / 4>(sl, rbase, w3a, w3b, KC4, HID / 4, S1a, S1b);
    __syncthreads();
#pragma unroll
    for (int r = 0; r < RPTB; ++r) {
      float cura = __fadd_rn(__fadd_rn(S0a[r], S1a[r]), bias3a);
      float curb = __fadd_rn(__fadd_rn(S0b[r], S1b[r]), bias3b);
      m3a[r] = __fadd_rn(__fmul_rn(0.95f, m3a[r]), cura);
      float sa = (m3a[r] > 1.0f) ? 1.0f : 0.0f;
      m3a[r] = __fsub_rn(m3a[r], sa);
      sca[r] = __fadd_rn(sca[r], sa);
      m3b[r] = __fadd_rn(__fmul_rn(0.95f, m3b[r]), curb);
      float sb = (m3b[r] > 1.0f) ? 1.0f : 0.0f;
      m3b[r] = __fsub_rn(m3b[r], sb);
      scb[r] = __fadd_rn(scb[r], sb);
    }
  }

#pragma unroll
  for (int r = 0; r < RPTB; ++r) {
    sl[(rbase + r) * HID + j1] = sca[r] * 0.125f;
    sl[(rbase + r) * HID + j2] = scb[r] * 0.125f;
  }
  __syncthreads();

  if (is_value == 0) {
    if (tid < ROWS * 6) {
      int r = tid / 6, k = tid % 6;
      const float* wr = Wh + (size_t)k * HID;
      float S0 = 0.f, S1 = 0.f;
      for (int i = 0; i < 4 * KC4; ++i)   S0 = fmaf(sl[r * HID + i], wr[i], S0);
      for (int i = 4 * KC4; i < HID; ++i) S1 = fmaf(sl[r * HID + i], wr[i], S1);
      out[(size_t)(r0 + r) * 6 + k] = __fadd_rn(__fadd_rn(S0, S1), bh[k]);
      out[(size_t)B * 6 + (size_t)(r0 + r) * 6 + k] = log_std[k];
    }
  } else {
    if (tid < ROWS) {
      int r = tid;
      float S0 = 0.f, S1 = 0.f;
      for (int i = 0; i < 4 * KC4; ++i)   S0 = fmaf(sl[r * HID + i], Wh[i], S0);
      for (int i = 4 * KC4; i < HID; ++i) S1 = fmaf(sl[r * HID + i], Wh[i], S1);
      out[(size_t)B * 12 + (size_t)(r0 + r)] = __fadd_rn(__fadd_rn(S0, S1), bh[0]);
    }
  }
}

extern "C" void kernel_launch(void* const* d_in, const int* in_sizes, int n_in,
                              void* d_out, int out_size, void* d_ws, size_t ws_size,
                              hipStream_t stream) {
  const float* obs = (const float*)d_in[0];
  const float* pw1 = (const float*)d_in[1];  const float* pb1 = (const float*)d_in[2];
  const float* pw2 = (const float*)d_in[3];  const float* pb2 = (const float*)d_in[4];
  const float* pw3 = (const float*)d_in[5];  const float* pb3 = (const float*)d_in[6];
  const float* aw  = (const float*)d_in[7];  const float* ab  = (const float*)d_in[8];
  const float* vw1 = (const float*)d_in[9];  const float* vb1 = (const float*)d_in[10];
  const float* vw2 = (const float*)d_in[11]; const float* vb2 = (const float*)d_in[12];
  const float* vw3 = (const float*)d_in[13]; const float* vb3 = (const float*)d_in[14];
  const float* hw  = (const float*)d_in[15]; const float* hb  = (const float*)d_in[16];
  const float* lsd = (const float*)d_in[17];
  float* out = (float*)d_out;

  const int B  = in_sizes[0] / IN_DIM;
  const int nb = B / ROWS;

  const size_t need = (size_t)(IN_DIM * HID + 2 * HID * HID) * 2 * sizeof(float);
  if (ws_size >= need && (nb & 3) == 0) {
    float* w = (float*)d_ws;
    float* pP1 = w;
    float* pP2 = w + 131072;
    float* pP3 = w + 393216;
    float* vP1 = w + 655360;
    float* vP2 = w + 786432;
    float* vP3 = w + 1048576;
    wpack4<<<dim3(IN_DIM / 32, 16), 256, 0, stream>>>(pw1, pP1, IN_DIM);
    wpack4<<<dim3(HID / 32, 16),    256, 0, stream>>>(pw2, pP2, HID);
    wpack4<<<dim3(HID / 32, 16),    256, 0, stream>>>(pw3, pP3, HID);
    wpack4<<<dim3(IN_DIM / 32, 16), 256, 0, stream>>>(vw1, vP1, IN_DIM);
    wpack4<<<dim3(HID / 32, 16),    256, 0, stream>>>(vw2, vP2, HID);
    wpack4<<<dim3(HID / 32, 16),    256, 0, stream>>>(vw3, vP3, HID);
    snn_net<<<2 * nb, NTHR, 0, stream>>>(obs,
        (const float4*)pP1, pb1, (const float4*)pP2, pb2, (const float4*)pP3, pb3, aw, ab,
        (const float4*)vP1, vb1, (const float4*)vP2, vb2, (const float4*)vP3, vb3, hw, hb,
        lsd, out, B);
  } else {
    dim3 grid(nb, 2);
    snn_net_base<<<grid, NTHRB, 0, stream>>>(obs,
        pw1, pb1, pw2, pb2, pw3, pb3, aw, ab,
        vw1, vb1, vw2, vb2, vw3, vb3, hw, hb,
        lsd, out, B);
  }
}

// Round 10
// 2544.111 us; speedup vs baseline: 1.6876x; 1.6876x over previous
//
#include <hip/hip_runtime.h>
#include <cstdint>
#include <cstddef>

#define IN_DIM 256
#define HID    512
#define TSTEPS 8
#define ROWS   16
#define NTHR   512     // 128 col-slots x 4 row-groups
#define RPT    4       // rows per thread
#define KC4    96      // OpenBLAS kc=384 boundary in floats/4 (head loops)

// ---- pack: Pf[(k*128+jj)*4 + c] = W[jj+128c][k]  (round-9 proven layout)
__global__ void wpack4(const float* __restrict__ W, float* __restrict__ Pf, int K) {
  __shared__ float tl[32][33];
  const int k0 = blockIdx.x * 32;
  const int j0 = blockIdx.y * 32;
  const int tx = threadIdx.x & 31, ty = threadIdx.x >> 5;
#pragma unroll
  for (int i = 0; i < 32; i += 8)
    tl[ty + i][tx] = W[(size_t)(j0 + ty + i) * K + (k0 + tx)];
  __syncthreads();
  const int c = j0 >> 7;
  const int jjb = j0 & 127;
#pragma unroll
  for (int i = 0; i < 32; i += 8) {
    int k = k0 + ty + i;
    Pf[((size_t)k * 128 + (jjb + tx)) * 4 + c] = tl[tx][ty + i];
  }
}

// ---- dense f32-obs GEMM (layer 1, K=256 single panel) — round-9 proven
__device__ __forceinline__ void gemm_obs(const float* __restrict__ obsT,
                                         int rbase, const float4* __restrict__ P,
                                         int j1, float (&A)[RPT][4]) {
#pragma unroll 1
  for (int i4 = 0; i4 < IN_DIM / 4; ++i4) {
    const float4* wp = P + ((size_t)i4 << 9) + j1;
    float4 w0 = wp[0], w1 = wp[128], w2 = wp[256], w3 = wp[384];
#pragma unroll
    for (int r = 0; r < RPT; ++r) {
      float4 o = *reinterpret_cast<const float4*>(obsT + ((rbase + r) << 8) + (i4 << 2));
      float a0 = A[r][0], a1 = A[r][1], a2 = A[r][2], a3 = A[r][3];
      a0 = fmaf(o.x, w0.x, a0); a1 = fmaf(o.x, w0.y, a1); a2 = fmaf(o.x, w0.z, a2); a3 = fmaf(o.x, w0.w, a3);
      a0 = fmaf(o.y, w1.x, a0); a1 = fmaf(o.y, w1.y, a1); a2 = fmaf(o.y, w1.z, a2); a3 = fmaf(o.y, w1.w, a3);
      a0 = fmaf(o.z, w2.x, a0); a1 = fmaf(o.z, w2.y, a1); a2 = fmaf(o.z, w2.z, a2); a3 = fmaf(o.z, w2.w, a3);
      a0 = fmaf(o.w, w3.x, a0); a1 = fmaf(o.w, w3.y, a1); a2 = fmaf(o.w, w3.z, a2); a3 = fmaf(o.w, w3.w, a3);
      A[r][0] = a0; A[r][1] = a1; A[r][2] = a2; A[r][3] = a3;
    }
  }
}

// ---- sparse helpers: 8-entry chunk load (k wave-uniform -> scalar addressing)
__device__ __forceinline__ void loadchunk(float4 (&w)[8], uint4 kw,
                                          const float4* __restrict__ P, int j1) {
  int s0 = __builtin_amdgcn_readfirstlane((int)kw.x);
  int s1 = __builtin_amdgcn_readfirstlane((int)kw.y);
  int s2 = __builtin_amdgcn_readfirstlane((int)kw.z);
  int s3 = __builtin_amdgcn_readfirstlane((int)kw.w);
  w[0] = P[((s0 & 0xffff) << 7) + j1];
  w[1] = P[((s0 >> 16) << 7) + j1];
  w[2] = P[((s1 & 0xffff) << 7) + j1];
  w[3] = P[((s1 >> 16) << 7) + j1];
  w[4] = P[((s2 & 0xffff) << 7) + j1];
  w[5] = P[((s2 >> 16) << 7) + j1];
  w[6] = P[((s3 & 0xffff) << 7) + j1];
  w[7] = P[((s3 >> 16) << 7) + j1];
}

// ascending-order adds (bit-exact: fadd == fma with spike 1.0)
__device__ __forceinline__ void consume8(const float4 (&w)[8], float (&A)[4]) {
#pragma unroll
  for (int kk = 0; kk < 8; ++kk) {
    A[0] = __fadd_rn(A[0], w[kk].x);
    A[1] = __fadd_rn(A[1], w[kk].y);
    A[2] = __fadd_rn(A[2], w[kk].z);
    A[3] = __fadd_rn(A[3], w[kk].w);
  }
}

// process one panel's list [0,n) at lp (u16 k-indices, ascending); dual-buffered
__device__ __forceinline__ void panel(const unsigned short* __restrict__ lp, int n,
                                      const float4* __restrict__ P, int j1,
                                      float (&A)[4]) {
  const uint4* kp = reinterpret_cast<const uint4*>(lp);
  int C = n >> 3;
  float4 wA[8], wB[8];
  if (C > 0) {
    loadchunk(wA, kp[0], P, j1);
    int ci = 0;
#pragma unroll 1
    for (; ci + 2 <= C; ci += 2) {
      loadchunk(wB, kp[ci + 1], P, j1);
      consume8(wA, A);
      if (ci + 2 < C) loadchunk(wA, kp[ci + 2], P, j1);
      consume8(wB, A);
    }
    if (ci < C) consume8(wA, A);
  }
#pragma unroll 1
  for (int e = C << 3; e < n; ++e) {
    int k = lp[e];
    float4 wt = P[(k << 7) + j1];
    A[0] = __fadd_rn(A[0], wt.x);
    A[1] = __fadd_rn(A[1], wt.y);
    A[2] = __fadd_rn(A[2], wt.z);
    A[3] = __fadd_rn(A[3], wt.w);
  }
}

__launch_bounds__(NTHR, 1)
__global__ void snn_net(const float* __restrict__ obs,
                        const float4* __restrict__ pP1, const float* __restrict__ pb1_,
                        const float4* __restrict__ pP2, const float* __restrict__ pb2_,
                        const float4* __restrict__ pP3, const float* __restrict__ pb3_,
                        const float* __restrict__ paw, const float* __restrict__ pab,
                        const float4* __restrict__ vP1, const float* __restrict__ vb1_,
                        const float4* __restrict__ vP2, const float* __restrict__ vb2_,
                        const float4* __restrict__ vP3, const float* __restrict__ vb3_,
                        const float* __restrict__ vhw, const float* __restrict__ vhb,
                        const float* __restrict__ log_std,
                        float* __restrict__ out, int B) {
  const int bid = blockIdx.x;
  const int xcd = bid & 7;
  const int is_value = xcd >> 2;
  const int tile = (bid >> 3) * 4 + (xcd & 3);
  const float4* P1 = is_value ? vP1 : pP1;  const float* b1 = is_value ? vb1_ : pb1_;
  const float4* P2 = is_value ? vP2 : pP2;  const float* b2 = is_value ? vb2_ : pb2_;
  const float4* P3 = is_value ? vP3 : pP3;  const float* b3 = is_value ? vb3_ : pb3_;
  const float* Wh  = is_value ? vhw : paw;  const float* bh = is_value ? vhb : pab;

  // LDS 64KB: obsT [0,16K) -> meanT [0,32K) after loop; spk u8 [32K,40K);
  // counts [40K,40K+128); list u16 [48K,64K): row*1KB, low panel [0,384), high [384,512)
  __shared__ __align__(16) unsigned char lraw[65536];
  float* obsT = (float*)lraw;
  float* meanT = (float*)lraw;
  unsigned char* spk = lraw + 32768;
  unsigned* cnts = (unsigned*)(lraw + 40960);      // n0[16], n[16] interleaved pairs
  unsigned short* listb = (unsigned short*)(lraw + 49152);

  const int tid = threadIdx.x;
  const int lane = tid & 63;
  const int wid = tid >> 6;
  const int j1 = tid & 127;
  const int rbase = (tid >> 7) * RPT;   // 0,4,8,12
  const int r0 = tile * ROWS;

  // ---- stage obs tile
  {
    const float4* src = reinterpret_cast<const float4*>(obs + (size_t)r0 * IN_DIM);
    float4* dst = reinterpret_cast<float4*>(obsT);
    for (int e = tid; e < ROWS * IN_DIM / 4; e += NTHR) dst[e] = src[e];
  }
  __syncthreads();

  // ---- layer-1 currents in REGISTERS (K=256 single BLAS panel, bias AFTER sum)
  float c1v[RPT][4];
  {
    float Sa[RPT][4];
#pragma unroll
    for (int r = 0; r < RPT; ++r)
#pragma unroll
      for (int c = 0; c < 4; ++c) Sa[r][c] = 0.f;
    gemm_obs(obsT, rbase, P1, j1, Sa);
    const float bb0 = b1[j1], bb1 = b1[j1 + 128], bb2 = b1[j1 + 256], bb3 = b1[j1 + 384];
#pragma unroll
    for (int r = 0; r < RPT; ++r) {
      c1v[r][0] = __fadd_rn(Sa[r][0], bb0);
      c1v[r][1] = __fadd_rn(Sa[r][1], bb1);
      c1v[r][2] = __fadd_rn(Sa[r][2], bb2);
      c1v[r][3] = __fadd_rn(Sa[r][3], bb3);
    }
  }
  __syncthreads();  // obs reads done

  float m1[RPT][4], m2[RPT][4], m3[RPT][4];
  unsigned cnt32[2] = {0u, 0u};
#pragma unroll
  for (int r = 0; r < RPT; ++r)
#pragma unroll
    for (int c = 0; c < 4; ++c) { m1[r][c] = 0.f; m2[r][c] = 0.f; m3[r][c] = 0.f; }

  const float bias2[4] = { b2[j1], b2[j1 + 128], b2[j1 + 256], b2[j1 + 384] };
  const float bias3[4] = { b3[j1], b3[j1 + 128], b3[j1 + 256], b3[j1 + 384] };

  // ---- list builder: wave handles rows 2*wid, 2*wid+1; ascending-k compaction
  auto build = [&]() {
#pragma unroll
    for (int rr = 0; rr < 2; ++rr) {
      int row = wid * 2 + rr;
      unsigned long long b8 =
          *reinterpret_cast<const unsigned long long*>(spk + (row << 9) + (lane << 3));
      int cnt = __popcll(b8);       // spike bytes are 0/1 -> popcount == count
      int S = cnt;
#pragma unroll
      for (int off = 1; off < 64; off <<= 1) {
        int tv = __shfl_up(S, off);
        if (lane >= off) S += tv;
      }
      int total = __shfl(S, 63);
      int lowtot = __shfl(S, 47);   // k < 384 <=> lane < 48
      int excl = S - cnt;
      unsigned short* lrow = listb + (row << 9);
      int pos = (lane < 48) ? excl : (384 + excl - lowtot);
#pragma unroll
      for (int b = 0; b < 8; ++b) {
        if ((b8 >> (8 * b)) & 1ull) {
          lrow[pos] = (unsigned short)((lane << 3) + b);
          ++pos;
        }
      }
      if (lane == 0) {
        cnts[row * 2] = (unsigned)lowtot;
        cnts[row * 2 + 1] = (unsigned)total;
      }
    }
  };

#pragma unroll 1
  for (int t = 0; t < TSTEPS; ++t) {
    // ---- LIF layer 1 (numpy order: mul, add, cmp, sub) -> spike u8 -> spk
#pragma unroll
    for (int r = 0; r < RPT; ++r)
#pragma unroll
      for (int c = 0; c < 4; ++c) {
        m1[r][c] = __fadd_rn(__fmul_rn(0.95f, m1[r][c]), c1v[r][c]);
        bool f = m1[r][c] > 1.0f;
        m1[r][c] = __fsub_rn(m1[r][c], f ? 1.0f : 0.0f);
        spk[((rbase + r) << 9) + j1 + (c << 7)] = f ? 1 : 0;
      }
    __syncthreads();   // spk ready; all waves past prior gemm3 (list safe to overwrite)
    build();
    __syncthreads();   // list(l1) ready

    // ---- layer 2: sparse panels (kc=384 split preserved), RN(S0+S1)+bias
#pragma unroll 1
    for (int r = 0; r < RPT; ++r) {
      int row = rbase + r;
      int nlow = (int)cnts[row * 2];
      int ntot = (int)cnts[row * 2 + 1];
      const unsigned short* lrow = listb + (row << 9);
      float A0[4] = {0.f, 0.f, 0.f, 0.f}, A1[4] = {0.f, 0.f, 0.f, 0.f};
      panel(lrow, nlow, P2, j1, A0);
      panel(lrow + 384, ntot - nlow, P2, j1, A1);
#pragma unroll
      for (int c = 0; c < 4; ++c) {
        float cur = __fadd_rn(__fadd_rn(A0[c], A1[c]), bias2[c]);
        m2[r][c] = __fadd_rn(__fmul_rn(0.95f, m2[r][c]), cur);
        bool f = m2[r][c] > 1.0f;
        m2[r][c] = __fsub_rn(m2[r][c], f ? 1.0f : 0.0f);
        spk[(row << 9) + j1 + (c << 7)] = f ? 1 : 0;   // spk free (list consumed)
      }
    }
    __syncthreads();   // spk(l2) ready; all gemm2 list reads done
    build();
    __syncthreads();   // list(l2) ready

    // ---- layer 3: sparse panels; packed spike counts
#pragma unroll 1
    for (int r = 0; r < RPT; ++r) {
      int row = rbase + r;
      int nlow = (int)cnts[row * 2];
      int ntot = (int)cnts[row * 2 + 1];
      const unsigned short* lrow = listb + (row << 9);
      float A0[4] = {0.f, 0.f, 0.f, 0.f}, A1[4] = {0.f, 0.f, 0.f, 0.f};
      panel(lrow, nlow, P3, j1, A0);
      panel(lrow + 384, ntot - nlow, P3, j1, A1);
#pragma unroll
      for (int c = 0; c < 4; ++c) {
        float cur = __fadd_rn(__fadd_rn(A0[c], A1[c]), bias3[c]);
        m3[r][c] = __fadd_rn(__fmul_rn(0.95f, m3[r][c]), cur);
        bool f = m3[r][c] > 1.0f;
        m3[r][c] = __fsub_rn(m3[r][c], f ? 1.0f : 0.0f);
        cnt32[r >> 1] += f ? (1u << (((r & 1) * 4 + c) * 4)) : 0u;
      }
    }
    // no barrier: next LIF1 writes spk only; its barrier fences the list overwrite
  }
  __syncthreads();

  // ---- mean spikes (count/8 exact)
#pragma unroll
  for (int r = 0; r < RPT; ++r)
#pragma unroll
    for (int c = 0; c < 4; ++c)
      meanT[(rbase + r) * HID + j1 + (c << 7)] =
          (float)((cnt32[r >> 1] >> (((r & 1) * 4 + c) * 4)) & 15u) * 0.125f;
  __syncthreads();

  // ---- heads (BLAS two-panel, kc=384)
  if (is_value == 0) {
    if (tid < ROWS * 6) {
      int r = tid / 6, k = tid % 6;
      const float* wr = Wh + (size_t)k * HID;
      float S0h = 0.f, S1h = 0.f;
      for (int i = 0; i < 4 * KC4; ++i)   S0h = fmaf(meanT[r * HID + i], wr[i], S0h);
      for (int i = 4 * KC4; i < HID; ++i) S1h = fmaf(meanT[r * HID + i], wr[i], S1h);
      out[(size_t)(r0 + r) * 6 + k] = __fadd_rn(__fadd_rn(S0h, S1h), bh[k]);
      out[(size_t)B * 6 + (size_t)(r0 + r) * 6 + k] = log_std[k];
    }
  } else {
    if (tid < ROWS) {
      int r = tid;
      float S0h = 0.f, S1h = 0.f;
      for (int i = 0; i < 4 * KC4; ++i)   S0h = fmaf(meanT[r * HID + i], Wh[i], S0h);
      for (int i = 4 * KC4; i < HID; ++i) S1h = fmaf(meanT[r * HID + i], Wh[i], S1h);
      out[(size_t)B * 12 + (size_t)(r0 + r)] = __fadd_rn(__fadd_rn(S0h, S1h), bh[0]);
    }
  }
}

// ---------------- fallback (round-3 kernel, proven) ----------------
#define NTHRB 512
#define RPTB  8
template<int PITCH4>
__device__ __forceinline__ void gemm_f32(const float* __restrict__ sl, int rbase,
                                         const float4* __restrict__ wra,
                                         const float4* __restrict__ wrb,
                                         int i4begin, int i4end,
                                         float a0[RPTB], float a1[RPTB]) {
  const float4* slv = reinterpret_cast<const float4*>(sl);
  for (int i4 = i4begin; i4 < i4end; ++i4) {
    float4 wa = wra[i4];
    float4 wb = wrb[i4];
#pragma unroll
    for (int r = 0; r < RPTB; ++r) {
      float4 s = slv[(rbase + r) * PITCH4 + i4];
      a0[r] = fmaf(s.w, wa.w, fmaf(s.z, wa.z, fmaf(s.y, wa.y, fmaf(s.x, wa.x, a0[r]))));
      a1[r] = fmaf(s.w, wb.w, fmaf(s.z, wb.z, fmaf(s.y, wb.y, fmaf(s.x, wb.x, a1[r]))));
    }
  }
}

__launch_bounds__(NTHRB, 2)
__global__ void snn_net_base(const float* __restrict__ obs,
                             const float* __restrict__ pW1, const float* __restrict__ pb1_,
                             const float* __restrict__ pW2, const float* __restrict__ pb2_,
                             const float* __restrict__ pW3, const float* __restrict__ pb3_,
                             const float* __restrict__ paw, const float* __restrict__ pab,
                             const float* __restrict__ vW1, const float* __restrict__ vb1_,
                             const float* __restrict__ vW2, const float* __restrict__ vb2_,
                             const float* __restrict__ vW3, const float* __restrict__ vb3_,
                             const float* __restrict__ vhw, const float* __restrict__ vhb,
                             const float* __restrict__ log_std,
                             float* __restrict__ out, int B) {
  const int is_value = blockIdx.y;
  const float* W1 = is_value ? vW1 : pW1;  const float* b1 = is_value ? vb1_ : pb1_;
  const float* W2 = is_value ? vW2 : pW2;  const float* b2 = is_value ? vb2_ : pb2_;
  const float* W3 = is_value ? vW3 : pW3;  const float* b3 = is_value ? vb3_ : pb3_;
  const float* Wh = is_value ? vhw : paw;  const float* bh = is_value ? vhb : pab;

  __shared__ float sl[ROWS * HID];
  const int tid = threadIdx.x;
  const int r0 = blockIdx.x * ROWS;
  const int j1 = tid & 255, j2 = j1 + 256;
  const int rbase = (tid >> 8) * RPTB;

  for (int e = tid; e < ROWS * IN_DIM; e += NTHRB)
    sl[e] = obs[(size_t)r0 * IN_DIM + e];
  __syncthreads();

  float c1a[RPTB], c1b[RPTB];
  {
    float Sa[RPTB], Sb[RPTB];
#pragma unroll
    for (int r = 0; r < RPTB; ++r) { Sa[r] = 0.f; Sb[r] = 0.f; }
    gemm_f32<IN_DIM / 4>(sl, rbase,
        reinterpret_cast<const float4*>(W1 + (size_t)j1 * IN_DIM),
        reinterpret_cast<const float4*>(W1 + (size_t)j2 * IN_DIM),
        0, IN_DIM / 4, Sa, Sb);
    const float ba = b1[j1], bb = b1[j2];
#pragma unroll
    for (int r = 0; r < RPTB; ++r) {
      c1a[r] = __fadd_rn(Sa[r], ba);
      c1b[r] = __fadd_rn(Sb[r], bb);
    }
  }
  __syncthreads();

  float m1a[RPTB], m1b[RPTB], m2a[RPTB], m2b[RPTB], m3a[RPTB], m3b[RPTB];
  float sca[RPTB], scb[RPTB];
#pragma unroll
  for (int r = 0; r < RPTB; ++r) {
    m1a[r] = 0.f; m1b[r] = 0.f; m2a[r] = 0.f; m2b[r] = 0.f;
    m3a[r] = 0.f; m3b[r] = 0.f; sca[r] = 0.f; scb[r] = 0.f;
  }

  const float4* w2a = reinterpret_cast<const float4*>(W2 + (size_t)j1 * HID);
  const float4* w2b = reinterpret_cast<const float4*>(W2 + (size_t)j2 * HID);
  const float4* w3a = reinterpret_cast<const float4*>(W3 + (size_t)j1 * HID);
  const float4* w3b = reinterpret_cast<const float4*>(W3 + (size_t)j2 * HID);
  const float bias2a = b2[j1], bias2b = b2[j2];
  const float bias3a = b3[j1], bias3b = b3[j2];

  for (int t = 0; t < TSTEPS; ++t) {
#pragma unroll
    for (int r = 0; r < RPTB; ++r) {
      m1a[r] = __fadd_rn(__fmul_rn(0.95f, m1a[r]), c1a[r]);
      float sa = (m1a[r] > 1.0f) ? 1.0f : 0.0f;
      m1a[r] = __fsub_rn(m1a[r], sa);
      sl[(rbase + r) * HID + j1] = sa;
      m1b[r] = __fadd_rn(__fmul_rn(0.95f, m1b[r]), c1b[r]);
      float sb = (m1b[r] > 1.0f) ? 1.0f : 0.0f;
      m1b[r] = __fsub_rn(m1b[r], sb);
      sl[(rbase + r) * HID + j2] = sb;
    }
    __syncthreads();

    float S0a[RPTB], S0b[RPTB], S1a[RPTB], S1b[RPTB];
#pragma unroll
    for (int r = 0; r < RPTB; ++r) { S0a[r] = 0.f; S0b[r] = 0.f; S1a[r] = 0.f; S1b[r] = 0.f; }
    gemm_f32<HID / 4>(sl, rbase, w2a, w2b, 0, KC4, S0a, S0b);
    gemm_f32<HID / 4>(sl, rbase, w2a, w2b, KC4, HID / 4, S1a, S1b);
    __syncthreads();
#pragma unroll
    for (int r = 0; r < RPTB; ++r) {
      float cura = __fadd_rn(__fadd_rn(S0a[r], S1a[r]), bias2a);
      float curb = __fadd_rn(__fadd_rn(S0b[r], S1b[r]), bias2b);
      m2a[r] = __fadd_rn(__fmul_rn(0.95f, m2a[r]), cura);
      float sa = (m2a[r] > 1.0f) ? 1.0f : 0.0f;
      m2a[r] = __fsub_rn(m2a[r], sa);
      sl[(rbase + r) * HID + j1] = sa;
      m2b[r] = __fadd_rn(__fmul_rn(0.95f, m2b[r]), curb);
      float sb = (m2b[r] > 1.0f) ? 1.0f : 0.0f;
      m2b[r] = __fsub_rn(m2b[r], sb);
      sl[(rbase + r) * HID + j2] = sb;
    }
    __syncthreads();

#pragma unroll
    for (int r = 0; r < RPTB; ++r) { S0a[r] = 0.f; S0b[r] = 0.f; S1a[r] = 0.f; S1b[r] = 0.f; }
    gemm_f32<HID / 4>(sl, rbase, w3a, w3b, 0, KC4, S0a, S0b);
    gemm_f32<HID / 4>(sl, rbase, w3a, w3b, KC4, HID / 4, S1a, S1b);
    __syncthreads();
#pragma unroll
    for (int r = 0; r < RPTB; ++r) {
      float cura = __fadd_rn(__fadd_rn(S0a[r], S1a[r]), bias3a);
      float curb = __fadd_rn(__fadd_rn(S0b[r], S1b[r]), bias3b);
      m3a[r] = __fadd_rn(__fmul_rn(0.95f, m3a[r]), cura);
      float sa = (m3a[r] > 1.0f) ? 1.0f : 0.0f;
      m3a[r] = __fsub_rn(m3a[r], sa);
      sca[r] = __fadd_rn(sca[r], sa);
      m3b[r] = __fadd_rn(__fmul_rn(0.95f, m3b[r]), curb);
      float sb = (m3b[r] > 1.0f) ? 1.0f : 0.0f;
      m3b[r] = __fsub_rn(m3b[r], sb);
      scb[r] = __fadd_rn(scb[r], sb);
    }
  }

#pragma unroll
  for (int r = 0; r < RPTB; ++r) {
    sl[(rbase + r) * HID + j1] = sca[r] * 0.125f;
    sl[(rbase + r) * HID + j2] = scb[r] * 0.125f;
  }
  __syncthreads();

  if (is_value == 0) {
    if (tid < ROWS * 6) {
      int r = tid / 6, k = tid % 6;
      const float* wr = Wh + (size_t)k * HID;
      float S0 = 0.f, S1 = 0.f;
      for (int i = 0; i < 4 * KC4; ++i)   S0 = fmaf(sl[r * HID + i], wr[i], S0);
      for (int i = 4 * KC4; i < HID; ++i) S1 = fmaf(sl[r * HID + i], wr[i], S1);
      out[(size_t)(r0 + r) * 6 + k] = __fadd_rn(__fadd_rn(S0, S1), bh[k]);
      out[(size_t)B * 6 + (size_t)(r0 + r) * 6 + k] = log_std[k];
    }
  } else {
    if (tid < ROWS) {
      int r = tid;
      float S0 = 0.f, S1 = 0.f;
      for (int i = 0; i < 4 * KC4; ++i)   S0 = fmaf(sl[r * HID + i], Wh[i], S0);
      for (int i = 4 * KC4; i < HID; ++i) S1 = fmaf(sl[r * HID + i], Wh[i], S1);
      out[(size_t)B * 12 + (size_t)(r0 + r)] = __fadd_rn(__fadd_rn(S0, S1), bh[0]);
    }
  }
}

extern "C" void kernel_launch(void* const* d_in, const int* in_sizes, int n_in,
                              void* d_out, int out_size, void* d_ws, size_t ws_size,
                              hipStream_t stream) {
  const float* obs = (const float*)d_in[0];
  const float* pw1 = (const float*)d_in[1];  const float* pb1 = (const float*)d_in[2];
  const float* pw2 = (const float*)d_in[3];  const float* pb2 = (const float*)d_in[4];
  const float* pw3 = (const float*)d_in[5];  const float* pb3 = (const float*)d_in[6];
  const float* aw  = (const float*)d_in[7];  const float* ab  = (const float*)d_in[8];
  const float* vw1 = (const float*)d_in[9];  const float* vb1 = (const float*)d_in[10];
  const float* vw2 = (const float*)d_in[11]; const float* vb2 = (const float*)d_in[12];
  const float* vw3 = (const float*)d_in[13]; const float* vb3 = (const float*)d_in[14];
  const float* hw  = (const float*)d_in[15]; const float* hb  = (const float*)d_in[16];
  const float* lsd = (const float*)d_in[17];
  float* out = (float*)d_out;

  const int B  = in_sizes[0] / IN_DIM;
  const int nb = B / ROWS;

  const size_t need = (size_t)(IN_DIM * HID + 2 * HID * HID) * 2 * sizeof(float);
  if (ws_size >= need && (nb & 3) == 0) {
    float* w = (float*)d_ws;
    float* pP1 = w;
    float* pP2 = w + 131072;
    float* pP3 = w + 393216;
    float* vP1 = w + 655360;
    float* vP2 = w + 786432;
    float* vP3 = w + 1048576;
    wpack4<<<dim3(IN_DIM / 32, 16), 256, 0, stream>>>(pw1, pP1, IN_DIM);
    wpack4<<<dim3(HID / 32, 16),    256, 0, stream>>>(pw2, pP2, HID);
    wpack4<<<dim3(HID / 32, 16),    256, 0, stream>>>(pw3, pP3, HID);
    wpack4<<<dim3(IN_DIM / 32, 16), 256, 0, stream>>>(vw1, vP1, IN_DIM);
    wpack4<<<dim3(HID / 32, 16),    256, 0, stream>>>(vw2, vP2, HID);
    wpack4<<<dim3(HID / 32, 16),    256, 0, stream>>>(vw3, vP3, HID);
    snn_net<<<2 * nb, NTHR, 0, stream>>>(obs,
        (const float4*)pP1, pb1, (const float4*)pP2, pb2, (const float4*)pP3, pb3, aw, ab,
        (const float4*)vP1, vb1, (const float4*)vP2, vb2, (const float4*)vP3, vb3, hw, hb,
        lsd, out, B);
  } else {
    dim3 grid(nb, 2);
    snn_net_base<<<grid, NTHRB, 0, stream>>>(obs,
        pw1, pb1, pw2, pb2, pw3, pb3, aw, ab,
        vw1, vb1, vw2, vb2, vw3, vb3, hw, hb,
        lsd, out, B);
  }
}